// Round 4
// baseline (354.887 us; speedup 1.0000x reference)
//
#include <hip/hip_runtime.h>
#include <hip/hip_bf16.h>

#define ALPHA   0.1f
#define S_DECAY 0.95f
#define P_DECAY 0.99f
#define D_EMB   768
#define DK      256

// ---- DPP wave-64 reduction helpers (validated rounds 1-3) ----
template<int ctrl, int row_mask>
__device__ __forceinline__ float dpp_add(float x) {
    int y = __builtin_amdgcn_update_dpp(0, __float_as_int(x), ctrl, row_mask, 0xF, true);
    return x + __int_as_float(y);
}

template<int N>
__device__ __forceinline__ void wave_allred_arr(float (&x)[N]) {
#pragma unroll
    for (int n = 0; n < N; ++n) x[n] = dpp_add<0xB1,  0xF>(x[n]);
#pragma unroll
    for (int n = 0; n < N; ++n) x[n] = dpp_add<0x4E,  0xF>(x[n]);
#pragma unroll
    for (int n = 0; n < N; ++n) x[n] = dpp_add<0x141, 0xF>(x[n]);
#pragma unroll
    for (int n = 0; n < N; ++n) x[n] = dpp_add<0x140, 0xF>(x[n]);
#pragma unroll
    for (int n = 0; n < N; ++n) x[n] = dpp_add<0x142, 0xA>(x[n]);
#pragma unroll
    for (int n = 0; n < N; ++n) x[n] = dpp_add<0x143, 0xC>(x[n]);
#pragma unroll
    for (int n = 0; n < N; ++n)
        x[n] = __int_as_float(__builtin_amdgcn_readlane(__float_as_int(x[n]), 63));
}

__device__ __forceinline__ float dot4v(const float4& a, const float4& b) {
    float t0 = a.x * b.x; t0 = fmaf(a.y, b.y, t0);
    float t1 = a.z * b.z; t1 = fmaf(a.w, b.w, t1);
    return t0 + t1;
}

__device__ __forceinline__ float rl(float x, int lane) {
    return __int_as_float(__builtin_amdgcn_readlane(__float_as_int(x), lane));
}

// ---------------- Kernel 1: fused GEMM + norms + paragraph means ----------------
// grid = P+1 blocks of 256. Block p computes sentences 5p..5p+4 (one paragraph):
// K,V rows -> V store, paragraph mean, row/para norms, USrev/UPrev/UPfwd/PV/SVv.
// Block P zeroes all pad regions + biasF.
__global__ __launch_bounds__(256) void prep_kernel(
    const float* __restrict__ emb,
    const float* __restrict__ Wk, const float* __restrict__ bk,
    const float* __restrict__ Wv, const float* __restrict__ bv,
    float* __restrict__ V, float* __restrict__ PV,
    float* __restrict__ USrev, float* __restrict__ UPrev, float* __restrict__ UPfwd,
    float* __restrict__ SVv, float* __restrict__ biasF,
    int T, int P, int PADS, int PADP)
{
    const int tid = threadIdx.x;
    const int p = blockIdx.x;
    if (p >= P) {
        int nS = (PADS - T) * DK;
        float* base = USrev + (size_t)T * DK;
        for (int i = tid; i < nS; i += 256) base[i] = 0.f;
        int nP = (PADP - P) * DK;
        float* b1 = UPrev + (size_t)P * DK;
        float* b2 = UPfwd + (size_t)P * DK;
        float* b3 = PV    + (size_t)P * DK;
        for (int i = tid; i < nP; i += 256) { b1[i] = 0.f; b2[i] = 0.f; b3[i] = 0.f; }
        for (int i = tid; i < PADP - P; i += 256) SVv[P + i] = 0.f;
        for (int i = tid; i < PADP; i += 256) biasF[i] = 0.f;
        return;
    }

    __shared__ float se[5][D_EMB];
    __shared__ float s_red[4][8];
    const int j  = tid;
    const int wave = tid >> 6, l = tid & 63;
    const int r0 = p * 5;

    for (int i = tid; i < 5 * D_EMB; i += 256) {
        int r = i / D_EMB, d = i - r * D_EMB;
        se[r][d] = emb[(size_t)(r0 + r) * D_EMB + d];
    }
    __syncthreads();

    float ak[5] = {0.f,0.f,0.f,0.f,0.f};
    float aw[5] = {0.f,0.f,0.f,0.f,0.f};
    for (int d = 0; d < D_EMB; d += 4) {
#pragma unroll
        for (int dd = 0; dd < 4; ++dd) {
            float wk = Wk[(size_t)(d + dd) * DK + j];
            float wv = Wv[(size_t)(d + dd) * DK + j];
#pragma unroll
            for (int s = 0; s < 5; ++s) {
                float e = se[s][d + dd];
                ak[s] = fmaf(e, wk, ak[s]);
                aw[s] = fmaf(e, wv, aw[s]);
            }
        }
    }
    float bkj = bk[j], bvj = bv[j];
    float kk[5], vv[5];
    float pk = 0.f, pv = 0.f;
#pragma unroll
    for (int s = 0; s < 5; ++s) {
        kk[s] = ak[s] + bkj; vv[s] = aw[s] + bvj;
        pk += kk[s]; pv += vv[s];
    }
    pk *= 0.2f; pv *= 0.2f;
#pragma unroll
    for (int s = 0; s < 5; ++s) V[(size_t)(r0 + s) * DK + j] = vv[s];
    PV[(size_t)p * DK + j] = pv;

    // block-wide reductions: 5 row sumsq, para sumsq, para v-sum
    float red[7] = { kk[0]*kk[0], kk[1]*kk[1], kk[2]*kk[2], kk[3]*kk[3], kk[4]*kk[4],
                     pk*pk, pv };
    wave_allred_arr(red);
    if (l == 0) {
#pragma unroll
        for (int n = 0; n < 7; ++n) s_red[wave][n] = red[n];
    }
    __syncthreads();
    float tot[7];
#pragma unroll
    for (int n = 0; n < 7; ++n)
        tot[n] = s_red[0][n] + s_red[1][n] + s_red[2][n] + s_red[3][n];

#pragma unroll
    for (int s = 0; s < 5; ++s) {
        float inv = 1.0f / fmaxf(sqrtf(tot[s]), 1e-12f);
        USrev[(size_t)(T - 1 - (r0 + s)) * DK + j] = kk[s] * inv;
    }
    float invp = 1.0f / fmaxf(sqrtf(tot[5]), 1e-12f);
    float u = pk * invp;
    UPfwd[(size_t)p * DK + j] = u;
    UPrev[(size_t)(P - 1 - p) * DK + j] = u;
    if (tid == 0) SVv[p] = tot[6];
}

// ------------- Kernel 2: chunk Gram matrices A = alpha * (scaled strictly-lower Gram) -------------
__global__ __launch_bounds__(256) void gram_kernel(
    const float* __restrict__ USrev, const float* __restrict__ UPrev,
    const float* __restrict__ UPfwd, const float* __restrict__ SVv,
    float* __restrict__ AS, float* __restrict__ APB, float* __restrict__ APF,
    float* __restrict__ biasF, int NCS, int NCP)
{
    int bid  = blockIdx.x;
    int tile = bid & 3, bc = bid >> 2;
    const float* U; float* A; int m, type;
    if (bc < NCS)            { type = 0; m = bc;              U = USrev; A = AS;  }
    else if (bc < NCS + NCP) { type = 1; m = bc - NCS;        U = UPrev; A = APB; }
    else                     { type = 2; m = bc - NCS - NCP;  U = UPfwd; A = APF; }
    int ti2 = tile >> 1, tj2 = tile & 1;
    int tr = threadIdx.x & 15, tc = threadIdx.x >> 4;
    int i0 = ti2 * 32 + tr * 2, j0 = tj2 * 32 + tc * 2;
    float* Ab = A + (size_t)m * 4096;

    if (ti2 == 0 && tj2 == 1) {
        Ab[(i0    ) * 64 + j0] = 0.f; Ab[(i0    ) * 64 + j0 + 1] = 0.f;
        Ab[(i0 + 1) * 64 + j0] = 0.f; Ab[(i0 + 1) * 64 + j0 + 1] = 0.f;
        return;
    }
    const float4* U4 = reinterpret_cast<const float4*>(U) + (size_t)m * 64 * 64;
    float d00 = 0.f, d01 = 0.f, d10 = 0.f, d11 = 0.f;
    for (int k = 0; k < 64; ++k) {
        float4 r0 = U4[(size_t)(i0    ) * 64 + k];
        float4 r1 = U4[(size_t)(i0 + 1) * 64 + k];
        float4 c0 = U4[(size_t)(j0    ) * 64 + k];
        float4 c1 = U4[(size_t)(j0 + 1) * 64 + k];
        d00 = fmaf(r0.x, c0.x, d00); d00 = fmaf(r0.y, c0.y, d00);
        d00 = fmaf(r0.z, c0.z, d00); d00 = fmaf(r0.w, c0.w, d00);
        d01 = fmaf(r0.x, c1.x, d01); d01 = fmaf(r0.y, c1.y, d01);
        d01 = fmaf(r0.z, c1.z, d01); d01 = fmaf(r0.w, c1.w, d01);
        d10 = fmaf(r1.x, c0.x, d10); d10 = fmaf(r1.y, c0.y, d10);
        d10 = fmaf(r1.z, c0.z, d10); d10 = fmaf(r1.w, c0.w, d10);
        d11 = fmaf(r1.x, c1.x, d11); d11 = fmaf(r1.y, c1.y, d11);
        d11 = fmaf(r1.z, c1.z, d11); d11 = fmaf(r1.w, c1.w, d11);
    }
    float g00, g01, g10, g11;
    if (type == 2) {
        g00 = (j0     < i0    ) ? powf(P_DECAY, (float)(i0     - j0    )) * d00 : 0.f;
        g01 = (j0 + 1 < i0    ) ? powf(P_DECAY, (float)(i0     - j0 - 1)) * d01 : 0.f;
        g10 = (j0     < i0 + 1) ? powf(P_DECAY, (float)(i0 + 1 - j0    )) * d10 : 0.f;
        g11 = (j0 + 1 < i0 + 1) ? powf(P_DECAY, (float)(i0 + 1 - j0 - 1)) * d11 : 0.f;
    } else {
        g00 = (j0     < i0    ) ? d00 : 0.f;
        g01 = (j0 + 1 < i0    ) ? d01 : 0.f;
        g10 = (j0     < i0 + 1) ? d10 : 0.f;
        g11 = (j0 + 1 < i0 + 1) ? d11 : 0.f;
    }
    Ab[(i0    ) * 64 + j0]     = ALPHA * g00;
    Ab[(i0    ) * 64 + j0 + 1] = ALPHA * g01;
    Ab[(i0 + 1) * 64 + j0]     = ALPHA * g10;
    Ab[(i0 + 1) * 64 + j0 + 1] = ALPHA * g11;
    if (type == 2) {
        float sv0 = SVv[m * 64 + j0], sv1 = SVv[m * 64 + j0 + 1];
        atomicAdd(&biasF[m * 64 + i0],     g00 * sv0 + g01 * sv1);
        atomicAdd(&biasF[m * 64 + i0 + 1], g10 * sv0 + g11 * sv1);
    }
}

// ------------- Kernel 3: sequential chunk solver, register double-buffered -------------
__global__ __launch_bounds__(256) void solve_kernel(
    const float* __restrict__ USrev, const float* __restrict__ UPrev,
    const float* __restrict__ UPfwd, const float* __restrict__ SVv,
    const float* __restrict__ AS, const float* __restrict__ APB,
    const float* __restrict__ APF, const float* __restrict__ biasF,
    const float* __restrict__ q,
    float* __restrict__ CS, float* __restrict__ CPB1, float* __restrict__ CPB2,
    float* __restrict__ gscal, float* __restrict__ out, int NCS, int NCP)
{
    __shared__ float s_b1[64], s_b2[64], s_c1[64], s_c2[64], s_hh[64];
    __shared__ float4 s_part[4][64], s_part2[4][64];
    __shared__ float s_powd[65];
    const int tid = threadIdx.x, wave = tid >> 6, l = tid & 63;
    if (tid <= 64) s_powd[tid] = powf(P_DECAY, (float)tid);

    float4 q4 = reinterpret_cast<const float4*>(q)[l];
    float qs[1] = { dot4v(q4, q4) };
    wave_allred_arr(qs);
    float qinv = 1.0f / fmaxf(sqrtf(qs[0]), 1e-12f);
    float4 qn = make_float4(q4.x * qinv, q4.y * qinv, q4.z * qinv, q4.w * qinv);
    __syncthreads();

    // ================= sentence backward =================
    {
        float4 w1 = qn;
        const float4* U4 = reinterpret_cast<const float4*>(USrev);
        float4 cur[16];
#pragma unroll
        for (int r = 0; r < 16; ++r)
            cur[r] = U4[(size_t)(wave * 16 + r) * 64 + l];
        for (int m = 0; m < NCS; ++m) {
            float4 nxt[16];
            if (m + 1 < NCS) {
                const float4* Un = U4 + (size_t)(m + 1) * 64 * 64;
#pragma unroll
                for (int r = 0; r < 16; ++r)
                    nxt[r] = Un[(size_t)(wave * 16 + r) * 64 + l];
            }
            float av[64];
            if (wave == 0) {
                const float4* Ar = reinterpret_cast<const float4*>(AS) + ((size_t)m * 64 + l) * 16;
#pragma unroll
                for (int r = 0; r < 16; ++r) {
                    float4 t = Ar[r];
                    av[4*r] = t.x; av[4*r+1] = t.y; av[4*r+2] = t.z; av[4*r+3] = t.w;
                }
            }
#pragma unroll
            for (int g = 0; g < 4; ++g) {
                float d[4];
#pragma unroll
                for (int r = 0; r < 4; ++r) d[r] = dot4v(cur[g * 4 + r], w1);
                wave_allred_arr(d);
                if (l == 0) {
                    int i0 = wave * 16 + g * 4;
                    s_b1[i0] = d[0]; s_b1[i0+1] = d[1]; s_b1[i0+2] = d[2]; s_b1[i0+3] = d[3];
                }
            }
            __syncthreads();
            if (wave == 0) {
                float ct = s_b1[l];
#pragma unroll
                for (int jj = 0; jj < 64; ++jj) {
                    float cj = rl(ct, jj);
                    ct = fmaf(-cj, av[jj], ct);
                }
                s_c1[l] = ct;
                CS[m * 64 + l] = ct;
            }
            __syncthreads();
            float4 acc = make_float4(0.f, 0.f, 0.f, 0.f);
#pragma unroll
            for (int r = 0; r < 16; ++r) {
                float ci = s_c1[wave * 16 + r];
                float4 u = cur[r];
                acc.x = fmaf(ci, u.x, acc.x); acc.y = fmaf(ci, u.y, acc.y);
                acc.z = fmaf(ci, u.z, acc.z); acc.w = fmaf(ci, u.w, acc.w);
            }
            s_part[wave][l] = acc;
            __syncthreads();
            float4 p0 = s_part[0][l], p1 = s_part[1][l], p2 = s_part[2][l], p3 = s_part[3][l];
            w1.x = fmaf(-ALPHA, p0.x + p1.x + p2.x + p3.x, w1.x);
            w1.y = fmaf(-ALPHA, p0.y + p1.y + p2.y + p3.y, w1.y);
            w1.z = fmaf(-ALPHA, p0.z + p1.z + p2.z + p3.z, w1.z);
            w1.w = fmaf(-ALPHA, p0.w + p1.w + p2.w + p3.w, w1.w);
            if (m + 1 < NCS) {
#pragma unroll
                for (int r = 0; r < 16; ++r) cur[r] = nxt[r];
            }
        }
    }

    // ================= paragraph backward (dual RHS) =================
    {
        float4 w1 = qn;
        float4 w2 = make_float4(1.f, 1.f, 1.f, 1.f);
        const float4* U4 = reinterpret_cast<const float4*>(UPrev);
        float4 cur[16];
#pragma unroll
        for (int r = 0; r < 16; ++r)
            cur[r] = U4[(size_t)(wave * 16 + r) * 64 + l];
        for (int m = 0; m < NCP; ++m) {
            float4 nxt[16];
            if (m + 1 < NCP) {
                const float4* Un = U4 + (size_t)(m + 1) * 64 * 64;
#pragma unroll
                for (int r = 0; r < 16; ++r)
                    nxt[r] = Un[(size_t)(wave * 16 + r) * 64 + l];
            }
            float av[64];
            if (wave == 0) {
                const float4* Ar = reinterpret_cast<const float4*>(APB) + ((size_t)m * 64 + l) * 16;
#pragma unroll
                for (int r = 0; r < 16; ++r) {
                    float4 t = Ar[r];
                    av[4*r] = t.x; av[4*r+1] = t.y; av[4*r+2] = t.z; av[4*r+3] = t.w;
                }
            }
#pragma unroll
            for (int g = 0; g < 4; ++g) {
                float d[8];
#pragma unroll
                for (int r = 0; r < 4; ++r) {
                    float4 u = cur[g * 4 + r];
                    d[r]     = dot4v(u, w1);
                    d[4 + r] = dot4v(u, w2);
                }
                wave_allred_arr(d);
                if (l == 0) {
                    int i0 = wave * 16 + g * 4;
#pragma unroll
                    for (int r = 0; r < 4; ++r) { s_b1[i0+r] = d[r]; s_b2[i0+r] = d[4+r]; }
                }
            }
            __syncthreads();
            if (wave == 0) {
                float ct1 = s_b1[l], ct2 = s_b2[l];
#pragma unroll
                for (int jj = 0; jj < 64; ++jj) {
                    float c1j = rl(ct1, jj);
                    float c2j = rl(ct2, jj);
                    float a = av[jj];
                    ct1 = fmaf(-c1j, a, ct1);
                    ct2 = fmaf(-c2j, a, ct2);
                }
                s_c1[l] = ct1; s_c2[l] = ct2;
                CPB1[m * 64 + l] = ct1; CPB2[m * 64 + l] = ct2;
            }
            __syncthreads();
            float4 a1 = make_float4(0.f,0.f,0.f,0.f), a2 = make_float4(0.f,0.f,0.f,0.f);
#pragma unroll
            for (int r = 0; r < 16; ++r) {
                int i = wave * 16 + r;
                float c1 = s_c1[i], c2 = s_c2[i];
                float4 u = cur[r];
                a1.x = fmaf(c1, u.x, a1.x); a1.y = fmaf(c1, u.y, a1.y);
                a1.z = fmaf(c1, u.z, a1.z); a1.w = fmaf(c1, u.w, a1.w);
                a2.x = fmaf(c2, u.x, a2.x); a2.y = fmaf(c2, u.y, a2.y);
                a2.z = fmaf(c2, u.z, a2.z); a2.w = fmaf(c2, u.w, a2.w);
            }
            s_part[wave][l] = a1; s_part2[wave][l] = a2;
            __syncthreads();
            {
                float4 p0 = s_part[0][l], p1 = s_part[1][l], p2 = s_part[2][l], p3 = s_part[3][l];
                w1.x = fmaf(-ALPHA, p0.x+p1.x+p2.x+p3.x, w1.x);
                w1.y = fmaf(-ALPHA, p0.y+p1.y+p2.y+p3.y, w1.y);
                w1.z = fmaf(-ALPHA, p0.z+p1.z+p2.z+p3.z, w1.z);
                w1.w = fmaf(-ALPHA, p0.w+p1.w+p2.w+p3.w, w1.w);
                float4 r0 = s_part2[0][l], r1 = s_part2[1][l], r2 = s_part2[2][l], r3 = s_part2[3][l];
                w2.x = fmaf(-ALPHA, r0.x+r1.x+r2.x+r3.x, w2.x);
                w2.y = fmaf(-ALPHA, r0.y+r1.y+r2.y+r3.y, w2.y);
                w2.z = fmaf(-ALPHA, r0.z+r1.z+r2.z+r3.z, w2.z);
                w2.w = fmaf(-ALPHA, r0.w+r1.w+r2.w+r3.w, w2.w);
            }
            if (m + 1 < NCP) {
#pragma unroll
                for (int r = 0; r < 16; ++r) cur[r] = nxt[r];
            }
        }
    }

    // ================= paragraph forward =================
    float4 y = make_float4(0.f, 0.f, 0.f, 0.f);
    {
        const float4* U4 = reinterpret_cast<const float4*>(UPfwd);
        float4 cur[16];
#pragma unroll
        for (int r = 0; r < 16; ++r)
            cur[r] = U4[(size_t)(wave * 16 + r) * 64 + l];
        for (int m = 0; m < NCP; ++m) {
            float4 nxt[16];
            if (m + 1 < NCP) {
                const float4* Un = U4 + (size_t)(m + 1) * 64 * 64;
#pragma unroll
                for (int r = 0; r < 16; ++r)
                    nxt[r] = Un[(size_t)(wave * 16 + r) * 64 + l];
            }
            float av[64]; float biasl = 0.f, svl = 0.f;
            if (wave == 0) {
                const float4* Ar = reinterpret_cast<const float4*>(APF) + ((size_t)m * 64 + l) * 16;
#pragma unroll
                for (int r = 0; r < 16; ++r) {
                    float4 t = Ar[r];
                    av[4*r] = t.x; av[4*r+1] = t.y; av[4*r+2] = t.z; av[4*r+3] = t.w;
                }
                biasl = biasF[m * 64 + l];
                svl   = SVv[m * 64 + l];
            }
#pragma unroll
            for (int g = 0; g < 4; ++g) {
                float d[4];
#pragma unroll
                for (int r = 0; r < 4; ++r) d[r] = dot4v(cur[g * 4 + r], y);
                wave_allred_arr(d);
                if (l == 0) {
                    int i0 = wave * 16 + g * 4;
                    s_b1[i0] = d[0]; s_b1[i0+1] = d[1]; s_b1[i0+2] = d[2]; s_b1[i0+3] = d[3];
                }
            }
            __syncthreads();
            if (wave == 0) {
                float ct = fmaf(s_powd[l + 1], s_b1[l], biasl);
#pragma unroll
                for (int jj = 0; jj < 64; ++jj) {
                    float cj = rl(ct, jj);
                    ct = fmaf(-cj, av[jj], ct);
                }
                s_hh[l] = s_powd[63 - l] * fmaf(-ALPHA, ct, svl);
            }
            __syncthreads();
            float4 acc = make_float4(0.f, 0.f, 0.f, 0.f);
#pragma unroll
            for (int r = 0; r < 16; ++r) {
                float hi = s_hh[wave * 16 + r];
                float4 u = cur[r];
                acc.x = fmaf(hi, u.x, acc.x); acc.y = fmaf(hi, u.y, acc.y);
                acc.z = fmaf(hi, u.z, acc.z); acc.w = fmaf(hi, u.w, acc.w);
            }
            s_part[wave][l] = acc;
            __syncthreads();
            float4 p0 = s_part[0][l], p1 = s_part[1][l], p2 = s_part[2][l], p3 = s_part[3][l];
            float d64 = s_powd[64];
            y.x = fmaf(d64, y.x, p0.x + p1.x + p2.x + p3.x);
            y.y = fmaf(d64, y.y, p0.y + p1.y + p2.y + p3.y);
            y.z = fmaf(d64, y.z, p0.z + p1.z + p2.z + p3.z);
            y.w = fmaf(d64, y.w, p0.w + p1.w + p2.w + p3.w);
            if (m + 1 < NCP) {
#pragma unroll
                for (int r = 0; r < 16; ++r) cur[r] = nxt[r];
            }
        }
    }
    float fin[2] = { dot4v(y, y), dot4v(qn, y) };
    wave_allred_arr(fin);
    if (tid == 0) gscal[0] = fin[1] / fmaxf(sqrtf(fin[0]), 2.56e-10f);
    out[tid] = 0.f;   // zero output for accum's atomics (out_size == 256)
}

// ------------- Kernel 4: parallel weighted accumulation -> atomic combine -------------
__global__ __launch_bounds__(256) void accum_kernel(
    const float* __restrict__ V, const float* __restrict__ PV,
    const float* __restrict__ CS, const float* __restrict__ CPB1,
    const float* __restrict__ CPB2, const float* __restrict__ gscal,
    float* __restrict__ out, int T, int P, int NCS, int NCP)
{
    __shared__ float wc[64];
    const int b = blockIdx.x, k = threadIdx.x;
    const float* src; const float* C; int i0, realN; float decay;
    if (b < NCS)            { src = V;  C = CS;   i0 = b * 64;               realN = T; decay = S_DECAY; }
    else if (b < NCS + NCP) { src = PV; C = CPB1; i0 = (b - NCS) * 64;       realN = P; decay = P_DECAY; }
    else                    { src = PV; C = CPB2; i0 = (b - NCS - NCP) * 64; realN = P; decay = P_DECAY; }
    if (k < 64) wc[k] = powf(decay, (float)(i0 + k)) * C[i0 + k];
    __syncthreads();
    float acc = 0.f;
    for (int ii = 0; ii < 64; ++ii) {
        int i = i0 + ii;
        if (i < realN)
            acc = fmaf(wc[ii], src[(size_t)(realN - 1 - i) * DK + k], acc);
    }
    float wlev;
    if (b < NCS)            wlev = 0.2f;
    else if (b < NCS + NCP) wlev = 0.3f;
    else                    wlev = (0.5f / 256.0f) * gscal[0];
    atomicAdd(&out[k], wlev * acc);
}

extern "C" void kernel_launch(void* const* d_in, const int* in_sizes, int n_in,
                              void* d_out, int out_size, void* d_ws, size_t ws_size,
                              hipStream_t stream) {
    const float* emb = (const float*)d_in[0];
    const float* q   = (const float*)d_in[1];
    const float* Wk  = (const float*)d_in[2];
    const float* bk  = (const float*)d_in[3];
    const float* Wv  = (const float*)d_in[4];
    const float* bv  = (const float*)d_in[5];

    const int T = in_sizes[0] / D_EMB;        // 1000
    const int P = T / 5;                      // 200
    const int NCS  = (T + 63) / 64;           // 16
    const int NCP  = (P + 63) / 64;           // 4
    const int PADS = NCS * 64;                // 1024
    const int PADP = NCP * 64;                // 256

    float* ws    = (float*)d_ws;
    float* V     = ws;                               // T*256
    float* PV    = V     + (size_t)T * DK;           // PADP*256
    float* USrev = PV    + (size_t)PADP * DK;        // PADS*256
    float* UPrev = USrev + (size_t)PADS * DK;        // PADP*256
    float* UPfwd = UPrev + (size_t)PADP * DK;        // PADP*256
    float* SVv   = UPfwd + (size_t)PADP * DK;        // PADP
    float* AS    = SVv   + PADP;                     // NCS*4096
    float* APB   = AS    + (size_t)NCS * 4096;       // NCP*4096
    float* APF   = APB   + (size_t)NCP * 4096;       // NCP*4096
    float* biasF = APF   + (size_t)NCP * 4096;       // PADP
    float* CS    = biasF + PADP;                     // PADS
    float* CPB1  = CS    + PADS;                     // PADP
    float* CPB2  = CPB1  + PADP;                     // PADP
    float* gscal = CPB2  + PADP;                     // 4

    prep_kernel<<<P + 1, 256, 0, stream>>>(emb, Wk, bk, Wv, bv,
                                           V, PV, USrev, UPrev, UPfwd, SVv, biasF,
                                           T, P, PADS, PADP);
    gram_kernel<<<(NCS + 2 * NCP) * 4, 256, 0, stream>>>(USrev, UPrev, UPfwd, SVv,
                                                         AS, APB, APF, biasF, NCS, NCP);
    solve_kernel<<<1, 256, 0, stream>>>(USrev, UPrev, UPfwd, SVv, AS, APB, APF, biasF, q,
                                        CS, CPB1, CPB2, gscal, (float*)d_out, NCS, NCP);
    accum_kernel<<<NCS + 2 * NCP, 256, 0, stream>>>(V, PV, CS, CPB1, CPB2, gscal,
                                                    (float*)d_out, T, P, NCS, NCP);
}

// Round 5
// 229.696 us; speedup vs baseline: 1.5450x; 1.5450x over previous
//
#include <hip/hip_runtime.h>
#include <hip/hip_bf16.h>

#define ALPHA   0.1f
#define S_DECAY 0.95f
#define P_DECAY 0.99f
#define D_EMB   768
#define DK      256

// ---- DPP wave-64 reduction helpers (validated rounds 1-4) ----
template<int ctrl, int row_mask>
__device__ __forceinline__ float dpp_add(float x) {
    int y = __builtin_amdgcn_update_dpp(0, __float_as_int(x), ctrl, row_mask, 0xF, true);
    return x + __int_as_float(y);
}

template<int N>
__device__ __forceinline__ void wave_allred_arr(float (&x)[N]) {
#pragma unroll
    for (int n = 0; n < N; ++n) x[n] = dpp_add<0xB1,  0xF>(x[n]);
#pragma unroll
    for (int n = 0; n < N; ++n) x[n] = dpp_add<0x4E,  0xF>(x[n]);
#pragma unroll
    for (int n = 0; n < N; ++n) x[n] = dpp_add<0x141, 0xF>(x[n]);
#pragma unroll
    for (int n = 0; n < N; ++n) x[n] = dpp_add<0x140, 0xF>(x[n]);
#pragma unroll
    for (int n = 0; n < N; ++n) x[n] = dpp_add<0x142, 0xA>(x[n]);
#pragma unroll
    for (int n = 0; n < N; ++n) x[n] = dpp_add<0x143, 0xC>(x[n]);
#pragma unroll
    for (int n = 0; n < N; ++n)
        x[n] = __int_as_float(__builtin_amdgcn_readlane(__float_as_int(x[n]), 63));
}

__device__ __forceinline__ float dot4v(const float4& a, const float4& b) {
    float t0 = a.x * b.x; t0 = fmaf(a.y, b.y, t0);
    float t1 = a.z * b.z; t1 = fmaf(a.w, b.w, t1);
    return t0 + t1;
}

__device__ __forceinline__ float rl(float x, int lane) {
    return __int_as_float(__builtin_amdgcn_readlane(__float_as_int(x), lane));
}

// ---------------- Kernel 1: GEMM (4 rows/block, scalar accums, SW-pipelined W loads)
//                  + fused K row-norm -> USrev ----------------
__global__ __launch_bounds__(256) void gemm_kv(
    const float* __restrict__ emb,
    const float* __restrict__ Wk, const float* __restrict__ bk,
    const float* __restrict__ Wv, const float* __restrict__ bv,
    float* __restrict__ K, float* __restrict__ V, float* __restrict__ USrev, int T)
{
    __shared__ float se[4][D_EMB];
    __shared__ float s_red[4][4];
    const int j  = threadIdx.x;
    const int wave = j >> 6, l = j & 63;
    const int r0 = blockIdx.x * 4;

    for (int i = j; i < 4 * D_EMB; i += 256) {
        int r = i / D_EMB, d = i - r * D_EMB;
        se[r][d] = emb[(size_t)(r0 + r) * D_EMB + d];
    }
    __syncthreads();

    const float* wkp = Wk + j;
    const float* wvp = Wv + j;

    float ak0 = 0.f, ak1 = 0.f, ak2 = 0.f, ak3 = 0.f;
    float av0 = 0.f, av1 = 0.f, av2 = 0.f, av3 = 0.f;

    // pipeline registers: current 4 wk + 4 wv values (explicit scalars)
    float a0 = wkp[0 * DK], a1 = wkp[1 * DK], a2 = wkp[2 * DK], a3 = wkp[3 * DK];
    float b0 = wvp[0 * DK], b1 = wvp[1 * DK], b2 = wvp[2 * DK], b3 = wvp[3 * DK];

    for (int d = 0; d < D_EMB; d += 4) {
        // prefetch next d-step's W values (wrap to 0 on last iter; values unused)
        int dn = (d + 4 < D_EMB) ? (d + 4) : 0;
        const float* wk2 = wkp + (size_t)dn * DK;
        const float* wv2 = wvp + (size_t)dn * DK;
        float na0 = wk2[0], na1 = wk2[DK], na2 = wk2[2 * DK], na3 = wk2[3 * DK];
        float nb0 = wv2[0], nb1 = wv2[DK], nb2 = wv2[2 * DK], nb3 = wv2[3 * DK];

        float4 e0 = *reinterpret_cast<const float4*>(&se[0][d]);
        float4 e1 = *reinterpret_cast<const float4*>(&se[1][d]);
        float4 e2 = *reinterpret_cast<const float4*>(&se[2][d]);
        float4 e3 = *reinterpret_cast<const float4*>(&se[3][d]);

        ak0 = fmaf(e0.x, a0, ak0); ak0 = fmaf(e0.y, a1, ak0);
        ak0 = fmaf(e0.z, a2, ak0); ak0 = fmaf(e0.w, a3, ak0);
        ak1 = fmaf(e1.x, a0, ak1); ak1 = fmaf(e1.y, a1, ak1);
        ak1 = fmaf(e1.z, a2, ak1); ak1 = fmaf(e1.w, a3, ak1);
        ak2 = fmaf(e2.x, a0, ak2); ak2 = fmaf(e2.y, a1, ak2);
        ak2 = fmaf(e2.z, a2, ak2); ak2 = fmaf(e2.w, a3, ak2);
        ak3 = fmaf(e3.x, a0, ak3); ak3 = fmaf(e3.y, a1, ak3);
        ak3 = fmaf(e3.z, a2, ak3); ak3 = fmaf(e3.w, a3, ak3);

        av0 = fmaf(e0.x, b0, av0); av0 = fmaf(e0.y, b1, av0);
        av0 = fmaf(e0.z, b2, av0); av0 = fmaf(e0.w, b3, av0);
        av1 = fmaf(e1.x, b0, av1); av1 = fmaf(e1.y, b1, av1);
        av1 = fmaf(e1.z, b2, av1); av1 = fmaf(e1.w, b3, av1);
        av2 = fmaf(e2.x, b0, av2); av2 = fmaf(e2.y, b1, av2);
        av2 = fmaf(e2.z, b2, av2); av2 = fmaf(e2.w, b3, av2);
        av3 = fmaf(e3.x, b0, av3); av3 = fmaf(e3.y, b1, av3);
        av3 = fmaf(e3.z, b2, av3); av3 = fmaf(e3.w, b3, av3);

        a0 = na0; a1 = na1; a2 = na2; a3 = na3;
        b0 = nb0; b1 = nb1; b2 = nb2; b3 = nb3;
    }

    float bkj = bk[j], bvj = bv[j];
    float kk0 = ak0 + bkj, kk1 = ak1 + bkj, kk2 = ak2 + bkj, kk3 = ak3 + bkj;
    float vv0 = av0 + bvj, vv1 = av1 + bvj, vv2 = av2 + bvj, vv3 = av3 + bvj;

    K[(size_t)(r0 + 0) * DK + j] = kk0;
    K[(size_t)(r0 + 1) * DK + j] = kk1;
    K[(size_t)(r0 + 2) * DK + j] = kk2;
    K[(size_t)(r0 + 3) * DK + j] = kk3;
    V[(size_t)(r0 + 0) * DK + j] = vv0;
    V[(size_t)(r0 + 1) * DK + j] = vv1;
    V[(size_t)(r0 + 2) * DK + j] = vv2;
    V[(size_t)(r0 + 3) * DK + j] = vv3;

    // fused K row-norms (block-wide reduction over the 256 columns)
    float red[4] = { kk0 * kk0, kk1 * kk1, kk2 * kk2, kk3 * kk3 };
    wave_allred_arr(red);
    if (l == 0) {
        s_red[wave][0] = red[0]; s_red[wave][1] = red[1];
        s_red[wave][2] = red[2]; s_red[wave][3] = red[3];
    }
    __syncthreads();
    float t0 = s_red[0][0] + s_red[1][0] + s_red[2][0] + s_red[3][0];
    float t1 = s_red[0][1] + s_red[1][1] + s_red[2][1] + s_red[3][1];
    float t2 = s_red[0][2] + s_red[1][2] + s_red[2][2] + s_red[3][2];
    float t3 = s_red[0][3] + s_red[1][3] + s_red[2][3] + s_red[3][3];
    float i0 = 1.0f / fmaxf(sqrtf(t0), 1e-12f);
    float i1 = 1.0f / fmaxf(sqrtf(t1), 1e-12f);
    float i2 = 1.0f / fmaxf(sqrtf(t2), 1e-12f);
    float i3 = 1.0f / fmaxf(sqrtf(t3), 1e-12f);
    USrev[(size_t)(T - 1 - (r0 + 0)) * DK + j] = kk0 * i0;
    USrev[(size_t)(T - 1 - (r0 + 1)) * DK + j] = kk1 * i1;
    USrev[(size_t)(T - 1 - (r0 + 2)) * DK + j] = kk2 * i2;
    USrev[(size_t)(T - 1 - (r0 + 3)) * DK + j] = kk3 * i3;
}

// ------------- Kernel 2: paragraph means/norms + pad zeroing -------------
// grid = PADP blocks of 64 threads.
__global__ __launch_bounds__(64) void para_kernel(
    const float* __restrict__ K, const float* __restrict__ V,
    float* __restrict__ PV, float* __restrict__ UPrev, float* __restrict__ UPfwd,
    float* __restrict__ SVv, float* __restrict__ biasF, int P, int PADP)
{
    const int l = threadIdx.x;
    const int p = blockIdx.x;
    const float4 z4 = make_float4(0.f, 0.f, 0.f, 0.f);
    if (p >= P) {
        reinterpret_cast<float4*>(PV)[(size_t)p * 64 + l]    = z4;
        reinterpret_cast<float4*>(UPfwd)[(size_t)p * 64 + l] = z4;
        reinterpret_cast<float4*>(UPrev)[(size_t)p * 64 + l] = z4;
        if (l == 0) SVv[p] = 0.f;
        if (p == P) {
            for (int i = l; i < PADP; i += 64) biasF[i] = 0.f;
        }
        return;
    }
    float4 pk = z4, pv = z4;
#pragma unroll
    for (int s = 0; s < 5; ++s) {
        float4 k4 = reinterpret_cast<const float4*>(K)[(size_t)(p * 5 + s) * 64 + l];
        float4 v4 = reinterpret_cast<const float4*>(V)[(size_t)(p * 5 + s) * 64 + l];
        pk.x += k4.x; pk.y += k4.y; pk.z += k4.z; pk.w += k4.w;
        pv.x += v4.x; pv.y += v4.y; pv.z += v4.z; pv.w += v4.w;
    }
    pk.x *= 0.2f; pk.y *= 0.2f; pk.z *= 0.2f; pk.w *= 0.2f;
    pv.x *= 0.2f; pv.y *= 0.2f; pv.z *= 0.2f; pv.w *= 0.2f;
    reinterpret_cast<float4*>(PV)[(size_t)p * 64 + l] = pv;
    float red[2] = { dot4v(pk, pk), pv.x + pv.y + pv.z + pv.w };
    wave_allred_arr(red);
    if (l == 0) SVv[p] = red[1];
    float inv = 1.0f / fmaxf(sqrtf(red[0]), 1e-12f);
    float4 u = make_float4(pk.x * inv, pk.y * inv, pk.z * inv, pk.w * inv);
    reinterpret_cast<float4*>(UPfwd)[(size_t)p * 64 + l] = u;
    reinterpret_cast<float4*>(UPrev)[(size_t)(P - 1 - p) * 64 + l] = u;
}

// ------------- Kernel 3: chunk Gram matrices A = alpha * (scaled strictly-lower Gram) -------------
__global__ __launch_bounds__(256) void gram_kernel(
    const float* __restrict__ USrev, const float* __restrict__ UPrev,
    const float* __restrict__ UPfwd, const float* __restrict__ SVv,
    float* __restrict__ AS, float* __restrict__ APB, float* __restrict__ APF,
    float* __restrict__ biasF, int NCS, int NCP)
{
    int bid  = blockIdx.x;
    int tile = bid & 3, bc = bid >> 2;
    const float* U; float* A; int m, type;
    if (bc < NCS)            { type = 0; m = bc;              U = USrev; A = AS;  }
    else if (bc < NCS + NCP) { type = 1; m = bc - NCS;        U = UPrev; A = APB; }
    else                     { type = 2; m = bc - NCS - NCP;  U = UPfwd; A = APF; }
    int ti2 = tile >> 1, tj2 = tile & 1;
    int tr = threadIdx.x & 15, tc = threadIdx.x >> 4;
    int i0 = ti2 * 32 + tr * 2, j0 = tj2 * 32 + tc * 2;
    float* Ab = A + (size_t)m * 4096;

    if (ti2 == 0 && tj2 == 1) {
        Ab[(i0    ) * 64 + j0] = 0.f; Ab[(i0    ) * 64 + j0 + 1] = 0.f;
        Ab[(i0 + 1) * 64 + j0] = 0.f; Ab[(i0 + 1) * 64 + j0 + 1] = 0.f;
        return;
    }
    const float4* U4 = reinterpret_cast<const float4*>(U) + (size_t)m * 64 * 64;
    float d00 = 0.f, d01 = 0.f, d10 = 0.f, d11 = 0.f;
    for (int k = 0; k < 64; ++k) {
        float4 r0 = U4[(size_t)(i0    ) * 64 + k];
        float4 r1 = U4[(size_t)(i0 + 1) * 64 + k];
        float4 c0 = U4[(size_t)(j0    ) * 64 + k];
        float4 c1 = U4[(size_t)(j0 + 1) * 64 + k];
        d00 = fmaf(r0.x, c0.x, d00); d00 = fmaf(r0.y, c0.y, d00);
        d00 = fmaf(r0.z, c0.z, d00); d00 = fmaf(r0.w, c0.w, d00);
        d01 = fmaf(r0.x, c1.x, d01); d01 = fmaf(r0.y, c1.y, d01);
        d01 = fmaf(r0.z, c1.z, d01); d01 = fmaf(r0.w, c1.w, d01);
        d10 = fmaf(r1.x, c0.x, d10); d10 = fmaf(r1.y, c0.y, d10);
        d10 = fmaf(r1.z, c0.z, d10); d10 = fmaf(r1.w, c0.w, d10);
        d11 = fmaf(r1.x, c1.x, d11); d11 = fmaf(r1.y, c1.y, d11);
        d11 = fmaf(r1.z, c1.z, d11); d11 = fmaf(r1.w, c1.w, d11);
    }
    float g00, g01, g10, g11;
    if (type == 2) {
        g00 = (j0     < i0    ) ? powf(P_DECAY, (float)(i0     - j0    )) * d00 : 0.f;
        g01 = (j0 + 1 < i0    ) ? powf(P_DECAY, (float)(i0     - j0 - 1)) * d01 : 0.f;
        g10 = (j0     < i0 + 1) ? powf(P_DECAY, (float)(i0 + 1 - j0    )) * d10 : 0.f;
        g11 = (j0 + 1 < i0 + 1) ? powf(P_DECAY, (float)(i0 + 1 - j0 - 1)) * d11 : 0.f;
    } else {
        g00 = (j0     < i0    ) ? d00 : 0.f;
        g01 = (j0 + 1 < i0    ) ? d01 : 0.f;
        g10 = (j0     < i0 + 1) ? d10 : 0.f;
        g11 = (j0 + 1 < i0 + 1) ? d11 : 0.f;
    }
    Ab[(i0    ) * 64 + j0]     = ALPHA * g00;
    Ab[(i0    ) * 64 + j0 + 1] = ALPHA * g01;
    Ab[(i0 + 1) * 64 + j0]     = ALPHA * g10;
    Ab[(i0 + 1) * 64 + j0 + 1] = ALPHA * g11;
    if (type == 2) {
        float sv0 = SVv[m * 64 + j0], sv1 = SVv[m * 64 + j0 + 1];
        atomicAdd(&biasF[m * 64 + i0],     g00 * sv0 + g01 * sv1);
        atomicAdd(&biasF[m * 64 + i0 + 1], g10 * sv0 + g11 * sv1);
    }
}

// ------------- Kernel 4: sequential chunk solver, register double-buffered -------------
__global__ __launch_bounds__(256) void solve_kernel(
    const float* __restrict__ USrev, const float* __restrict__ UPrev,
    const float* __restrict__ UPfwd, const float* __restrict__ SVv,
    const float* __restrict__ AS, const float* __restrict__ APB,
    const float* __restrict__ APF, const float* __restrict__ biasF,
    const float* __restrict__ q,
    float* __restrict__ CS, float* __restrict__ CPB1, float* __restrict__ CPB2,
    float* __restrict__ gscal, float* __restrict__ out, int NCS, int NCP)
{
    __shared__ float s_b1[64], s_b2[64], s_c1[64], s_c2[64], s_hh[64];
    __shared__ float4 s_part[4][64], s_part2[4][64];
    __shared__ float s_powd[65];
    const int tid = threadIdx.x, wave = tid >> 6, l = tid & 63;
    if (tid <= 64) s_powd[tid] = powf(P_DECAY, (float)tid);

    float4 q4 = reinterpret_cast<const float4*>(q)[l];
    float qs[1] = { dot4v(q4, q4) };
    wave_allred_arr(qs);
    float qinv = 1.0f / fmaxf(sqrtf(qs[0]), 1e-12f);
    float4 qn = make_float4(q4.x * qinv, q4.y * qinv, q4.z * qinv, q4.w * qinv);
    __syncthreads();

    // ================= sentence backward =================
    {
        float4 w1 = qn;
        const float4* U4 = reinterpret_cast<const float4*>(USrev);
        float4 cur[16];
#pragma unroll
        for (int r = 0; r < 16; ++r)
            cur[r] = U4[(size_t)(wave * 16 + r) * 64 + l];
        for (int m = 0; m < NCS; ++m) {
            float4 nxt[16];
            if (m + 1 < NCS) {
                const float4* Un = U4 + (size_t)(m + 1) * 64 * 64;
#pragma unroll
                for (int r = 0; r < 16; ++r)
                    nxt[r] = Un[(size_t)(wave * 16 + r) * 64 + l];
            }
            float av[64];
            if (wave == 0) {
                const float4* Ar = reinterpret_cast<const float4*>(AS) + ((size_t)m * 64 + l) * 16;
#pragma unroll
                for (int r = 0; r < 16; ++r) {
                    float4 t = Ar[r];
                    av[4*r] = t.x; av[4*r+1] = t.y; av[4*r+2] = t.z; av[4*r+3] = t.w;
                }
            }
#pragma unroll
            for (int g = 0; g < 4; ++g) {
                float d[4];
#pragma unroll
                for (int r = 0; r < 4; ++r) d[r] = dot4v(cur[g * 4 + r], w1);
                wave_allred_arr(d);
                if (l == 0) {
                    int i0 = wave * 16 + g * 4;
                    s_b1[i0] = d[0]; s_b1[i0+1] = d[1]; s_b1[i0+2] = d[2]; s_b1[i0+3] = d[3];
                }
            }
            __syncthreads();
            if (wave == 0) {
                float ct = s_b1[l];
#pragma unroll
                for (int jj = 0; jj < 64; ++jj) {
                    float cj = rl(ct, jj);
                    ct = fmaf(-cj, av[jj], ct);
                }
                s_c1[l] = ct;
                CS[m * 64 + l] = ct;
            }
            __syncthreads();
            float4 acc = make_float4(0.f, 0.f, 0.f, 0.f);
#pragma unroll
            for (int r = 0; r < 16; ++r) {
                float ci = s_c1[wave * 16 + r];
                float4 u = cur[r];
                acc.x = fmaf(ci, u.x, acc.x); acc.y = fmaf(ci, u.y, acc.y);
                acc.z = fmaf(ci, u.z, acc.z); acc.w = fmaf(ci, u.w, acc.w);
            }
            s_part[wave][l] = acc;
            __syncthreads();
            float4 p0 = s_part[0][l], p1 = s_part[1][l], p2 = s_part[2][l], p3 = s_part[3][l];
            w1.x = fmaf(-ALPHA, p0.x + p1.x + p2.x + p3.x, w1.x);
            w1.y = fmaf(-ALPHA, p0.y + p1.y + p2.y + p3.y, w1.y);
            w1.z = fmaf(-ALPHA, p0.z + p1.z + p2.z + p3.z, w1.z);
            w1.w = fmaf(-ALPHA, p0.w + p1.w + p2.w + p3.w, w1.w);
            if (m + 1 < NCS) {
#pragma unroll
                for (int r = 0; r < 16; ++r) cur[r] = nxt[r];
            }
        }
    }

    // ================= paragraph backward (dual RHS) =================
    {
        float4 w1 = qn;
        float4 w2 = make_float4(1.f, 1.f, 1.f, 1.f);
        const float4* U4 = reinterpret_cast<const float4*>(UPrev);
        float4 cur[16];
#pragma unroll
        for (int r = 0; r < 16; ++r)
            cur[r] = U4[(size_t)(wave * 16 + r) * 64 + l];
        for (int m = 0; m < NCP; ++m) {
            float4 nxt[16];
            if (m + 1 < NCP) {
                const float4* Un = U4 + (size_t)(m + 1) * 64 * 64;
#pragma unroll
                for (int r = 0; r < 16; ++r)
                    nxt[r] = Un[(size_t)(wave * 16 + r) * 64 + l];
            }
            float av[64];
            if (wave == 0) {
                const float4* Ar = reinterpret_cast<const float4*>(APB) + ((size_t)m * 64 + l) * 16;
#pragma unroll
                for (int r = 0; r < 16; ++r) {
                    float4 t = Ar[r];
                    av[4*r] = t.x; av[4*r+1] = t.y; av[4*r+2] = t.z; av[4*r+3] = t.w;
                }
            }
#pragma unroll
            for (int g = 0; g < 4; ++g) {
                float d[8];
#pragma unroll
                for (int r = 0; r < 4; ++r) {
                    float4 u = cur[g * 4 + r];
                    d[r]     = dot4v(u, w1);
                    d[4 + r] = dot4v(u, w2);
                }
                wave_allred_arr(d);
                if (l == 0) {
                    int i0 = wave * 16 + g * 4;
#pragma unroll
                    for (int r = 0; r < 4; ++r) { s_b1[i0+r] = d[r]; s_b2[i0+r] = d[4+r]; }
                }
            }
            __syncthreads();
            if (wave == 0) {
                float ct1 = s_b1[l], ct2 = s_b2[l];
#pragma unroll
                for (int jj = 0; jj < 64; ++jj) {
                    float c1j = rl(ct1, jj);
                    float c2j = rl(ct2, jj);
                    float a = av[jj];
                    ct1 = fmaf(-c1j, a, ct1);
                    ct2 = fmaf(-c2j, a, ct2);
                }
                s_c1[l] = ct1; s_c2[l] = ct2;
                CPB1[m * 64 + l] = ct1; CPB2[m * 64 + l] = ct2;
            }
            __syncthreads();
            float4 a1 = make_float4(0.f,0.f,0.f,0.f), a2 = make_float4(0.f,0.f,0.f,0.f);
#pragma unroll
            for (int r = 0; r < 16; ++r) {
                int i = wave * 16 + r;
                float c1 = s_c1[i], c2 = s_c2[i];
                float4 u = cur[r];
                a1.x = fmaf(c1, u.x, a1.x); a1.y = fmaf(c1, u.y, a1.y);
                a1.z = fmaf(c1, u.z, a1.z); a1.w = fmaf(c1, u.w, a1.w);
                a2.x = fmaf(c2, u.x, a2.x); a2.y = fmaf(c2, u.y, a2.y);
                a2.z = fmaf(c2, u.z, a2.z); a2.w = fmaf(c2, u.w, a2.w);
            }
            s_part[wave][l] = a1; s_part2[wave][l] = a2;
            __syncthreads();
            {
                float4 p0 = s_part[0][l], p1 = s_part[1][l], p2 = s_part[2][l], p3 = s_part[3][l];
                w1.x = fmaf(-ALPHA, p0.x+p1.x+p2.x+p3.x, w1.x);
                w1.y = fmaf(-ALPHA, p0.y+p1.y+p2.y+p3.y, w1.y);
                w1.z = fmaf(-ALPHA, p0.z+p1.z+p2.z+p3.z, w1.z);
                w1.w = fmaf(-ALPHA, p0.w+p1.w+p2.w+p3.w, w1.w);
                float4 r0 = s_part2[0][l], r1 = s_part2[1][l], r2 = s_part2[2][l], r3 = s_part2[3][l];
                w2.x = fmaf(-ALPHA, r0.x+r1.x+r2.x+r3.x, w2.x);
                w2.y = fmaf(-ALPHA, r0.y+r1.y+r2.y+r3.y, w2.y);
                w2.z = fmaf(-ALPHA, r0.z+r1.z+r2.z+r3.z, w2.z);
                w2.w = fmaf(-ALPHA, r0.w+r1.w+r2.w+r3.w, w2.w);
            }
            if (m + 1 < NCP) {
#pragma unroll
                for (int r = 0; r < 16; ++r) cur[r] = nxt[r];
            }
        }
    }

    // ================= paragraph forward =================
    float4 y = make_float4(0.f, 0.f, 0.f, 0.f);
    {
        const float4* U4 = reinterpret_cast<const float4*>(UPfwd);
        float4 cur[16];
#pragma unroll
        for (int r = 0; r < 16; ++r)
            cur[r] = U4[(size_t)(wave * 16 + r) * 64 + l];
        for (int m = 0; m < NCP; ++m) {
            float4 nxt[16];
            if (m + 1 < NCP) {
                const float4* Un = U4 + (size_t)(m + 1) * 64 * 64;
#pragma unroll
                for (int r = 0; r < 16; ++r)
                    nxt[r] = Un[(size_t)(wave * 16 + r) * 64 + l];
            }
            float av[64]; float biasl = 0.f, svl = 0.f;
            if (wave == 0) {
                const float4* Ar = reinterpret_cast<const float4*>(APF) + ((size_t)m * 64 + l) * 16;
#pragma unroll
                for (int r = 0; r < 16; ++r) {
                    float4 t = Ar[r];
                    av[4*r] = t.x; av[4*r+1] = t.y; av[4*r+2] = t.z; av[4*r+3] = t.w;
                }
                biasl = biasF[m * 64 + l];
                svl   = SVv[m * 64 + l];
            }
#pragma unroll
            for (int g = 0; g < 4; ++g) {
                float d[4];
#pragma unroll
                for (int r = 0; r < 4; ++r) d[r] = dot4v(cur[g * 4 + r], y);
                wave_allred_arr(d);
                if (l == 0) {
                    int i0 = wave * 16 + g * 4;
                    s_b1[i0] = d[0]; s_b1[i0+1] = d[1]; s_b1[i0+2] = d[2]; s_b1[i0+3] = d[3];
                }
            }
            __syncthreads();
            if (wave == 0) {
                float ct = fmaf(s_powd[l + 1], s_b1[l], biasl);
#pragma unroll
                for (int jj = 0; jj < 64; ++jj) {
                    float cj = rl(ct, jj);
                    ct = fmaf(-cj, av[jj], ct);
                }
                s_hh[l] = s_powd[63 - l] * fmaf(-ALPHA, ct, svl);
            }
            __syncthreads();
            float4 acc = make_float4(0.f, 0.f, 0.f, 0.f);
#pragma unroll
            for (int r = 0; r < 16; ++r) {
                float hi = s_hh[wave * 16 + r];
                float4 u = cur[r];
                acc.x = fmaf(hi, u.x, acc.x); acc.y = fmaf(hi, u.y, acc.y);
                acc.z = fmaf(hi, u.z, acc.z); acc.w = fmaf(hi, u.w, acc.w);
            }
            s_part[wave][l] = acc;
            __syncthreads();
            float4 p0 = s_part[0][l], p1 = s_part[1][l], p2 = s_part[2][l], p3 = s_part[3][l];
            float d64 = s_powd[64];
            y.x = fmaf(d64, y.x, p0.x + p1.x + p2.x + p3.x);
            y.y = fmaf(d64, y.y, p0.y + p1.y + p2.y + p3.y);
            y.z = fmaf(d64, y.z, p0.z + p1.z + p2.z + p3.z);
            y.w = fmaf(d64, y.w, p0.w + p1.w + p2.w + p3.w);
            if (m + 1 < NCP) {
#pragma unroll
                for (int r = 0; r < 16; ++r) cur[r] = nxt[r];
            }
        }
    }
    float fin[2] = { dot4v(y, y), dot4v(qn, y) };
    wave_allred_arr(fin);
    if (tid == 0) gscal[0] = fin[1] / fmaxf(sqrtf(fin[0]), 2.56e-10f);
    out[tid] = 0.f;   // zero output for accum's atomics (out_size == 256)
}

// ------------- Kernel 5: parallel weighted accumulation -> atomic combine -------------
__global__ __launch_bounds__(256) void accum_kernel(
    const float* __restrict__ V, const float* __restrict__ PV,
    const float* __restrict__ CS, const float* __restrict__ CPB1,
    const float* __restrict__ CPB2, const float* __restrict__ gscal,
    float* __restrict__ out, int T, int P, int NCS, int NCP)
{
    __shared__ float wc[64];
    const int b = blockIdx.x, k = threadIdx.x;
    const float* src; const float* C; int i0, realN; float decay;
    if (b < NCS)            { src = V;  C = CS;   i0 = b * 64;               realN = T; decay = S_DECAY; }
    else if (b < NCS + NCP) { src = PV; C = CPB1; i0 = (b - NCS) * 64;       realN = P; decay = P_DECAY; }
    else                    { src = PV; C = CPB2; i0 = (b - NCS - NCP) * 64; realN = P; decay = P_DECAY; }
    if (k < 64) wc[k] = powf(decay, (float)(i0 + k)) * C[i0 + k];
    __syncthreads();
    float acc = 0.f;
    for (int ii = 0; ii < 64; ++ii) {
        int i = i0 + ii;
        if (i < realN)
            acc = fmaf(wc[ii], src[(size_t)(realN - 1 - i) * DK + k], acc);
    }
    float wlev;
    if (b < NCS)            wlev = 0.2f;
    else if (b < NCS + NCP) wlev = 0.3f;
    else                    wlev = (0.5f / 256.0f) * gscal[0];
    atomicAdd(&out[k], wlev * acc);
}

extern "C" void kernel_launch(void* const* d_in, const int* in_sizes, int n_in,
                              void* d_out, int out_size, void* d_ws, size_t ws_size,
                              hipStream_t stream) {
    const float* emb = (const float*)d_in[0];
    const float* q   = (const float*)d_in[1];
    const float* Wk  = (const float*)d_in[2];
    const float* bk  = (const float*)d_in[3];
    const float* Wv  = (const float*)d_in[4];
    const float* bv  = (const float*)d_in[5];

    const int T = in_sizes[0] / D_EMB;        // 1000
    const int P = T / 5;                      // 200
    const int NCS  = (T + 63) / 64;           // 16
    const int NCP  = (P + 63) / 64;           // 4
    const int PADS = NCS * 64;                // 1024
    const int PADP = NCP * 64;                // 256

    float* ws    = (float*)d_ws;
    float* K     = ws;                               // T*256
    float* V     = K     + (size_t)T * DK;           // T*256
    float* PV    = V     + (size_t)T * DK;           // PADP*256
    float* USrev = PV    + (size_t)PADP * DK;        // PADS*256
    float* UPrev = USrev + (size_t)PADS * DK;        // PADP*256
    float* UPfwd = UPrev + (size_t)PADP * DK;        // PADP*256
    float* SVv   = UPfwd + (size_t)PADP * DK;        // PADP
    float* AS    = SVv   + PADP;                     // NCS*4096
    float* APB   = AS    + (size_t)NCS * 4096;       // NCP*4096
    float* APF   = APB   + (size_t)NCP * 4096;       // NCP*4096
    float* biasF = APF   + (size_t)NCP * 4096;       // PADP
    float* CS    = biasF + PADP;                     // PADS
    float* CPB1  = CS    + PADS;                     // PADP
    float* CPB2  = CPB1  + PADP;                     // PADP
    float* gscal = CPB2  + PADP;                     // 4

    gemm_kv<<<T / 4, 256, 0, stream>>>(emb, Wk, bk, Wv, bv, K, V, USrev, T);
    para_kernel<<<PADP, 64, 0, stream>>>(K, V, PV, UPrev, UPfwd, SVv, biasF, P, PADP);
    gram_kernel<<<(NCS + 2 * NCP) * 4, 256, 0, stream>>>(USrev, UPrev, UPfwd, SVv,
                                                         AS, APB, APF, biasF, NCS, NCP);
    solve_kernel<<<1, 256, 0, stream>>>(USrev, UPrev, UPfwd, SVv, AS, APB, APF, biasF, q,
                                        CS, CPB1, CPB2, gscal, (float*)d_out, NCS, NCP);
    accum_kernel<<<NCS + 2 * NCP, 256, 0, stream>>>(V, PV, CS, CPB1, CPB2, gscal,
                                                    (float*)d_out, T, P, NCS, NCP);
}